// Round 11
// baseline (414.337 us; speedup 1.0000x reference)
//
#include <hip/hip_runtime.h>
#include <hip/hip_bf16.h>
#include <math.h>

// Problem constants: b=8, t=512, d=128, h=8
#define BB 8
#define TT 512
#define DD 128
#define HH 8
#define OO 2048          // h*2*d
#define WCOLS 129        // d+1
#define SCALE 0.08838834764831845f   // 1/sqrt(128)
#define IT 16            // i-tile rows per flash block
#define SC2 64           // s-chunk (score indexing granularity)
#define NC (TT / SC2)    // 8 chunks
// u16 quantization: u = (v + 16) * 2048, step 4.88e-4, range +-16
#define QOFF 32768.0f
#define QSCL 2048.0f
#define SCALE_Q (SCALE / QSCL)

// dynamic LDS carve: kp = 512 rows x 66 uints (rotated), ps = 16 x 520 ushort
#define KP_UINTS (512 * 66)
#define KP_BYTES (KP_UINTS * 4)            // 135168
#define PS_BYTES (IT * (TT + 8) * 2)       // 16640
#define SH_BYTES (KP_BYTES + PS_BYTES)     // 151808 <= 160 KiB

typedef __attribute__((ext_vector_type(8))) short short8;
typedef __attribute__((ext_vector_type(4))) float floatx4;

static __device__ __forceinline__ float bf2f(__hip_bfloat16 v) { return __bfloat162float(v); }
static __device__ __forceinline__ float us2f(unsigned short u) {
  union { unsigned int i; float f; } cv; cv.i = ((unsigned int)u) << 16; return cv.f;
}
static __device__ __forceinline__ unsigned short f2us(float f) {
  union { float f; unsigned int i; } cv; cv.f = f;
  unsigned int lsb = (cv.i >> 16) & 1u;
  return (unsigned short)((cv.i + 0x7fffu + lsb) >> 16);   // RNE
}
// dtype-adaptive input load: isf=1 -> f32 buffer, isf=0 -> bf16 buffer
static __device__ __forceinline__ float ldin(const void* p, int i, int isf) {
  return isf ? ((const float*)p)[i] : bf2f(((const __hip_bfloat16*)p)[i]);
}
static __device__ __forceinline__ unsigned int quant1(float v) {
  float f = fminf(fmaxf(v * QSCL + QOFF, 0.0f), 65535.0f);
  return (unsigned int)(f + 0.5f);
}

#if __has_builtin(__builtin_amdgcn_sad_u16)
#define SAD16(a, b, c) __builtin_amdgcn_sad_u16((a), (b), (c))
#else
static __device__ __forceinline__ unsigned int SAD16(unsigned int a, unsigned int b, unsigned int c) {
  int d0 = (int)(a & 0xFFFFu) - (int)(b & 0xFFFFu);
  int d1 = (int)(a >> 16) - (int)(b >> 16);
  return c + (unsigned int)(d0 < 0 ? -d0 : d0) + (unsigned int)(d1 < 0 ? -d1 : d1);
}
#endif

// ---------------- K-1: detect input dtype (parallel; see R2 post-mortem) ----------------
__global__ void k_detect(const void* __restrict__ x, int* __restrict__ flag) {
  __shared__ int cnt;
  if (threadIdx.x == 0) cnt = 0;
  __syncthreads();
  const unsigned int* w = (const unsigned int*)x;
  float v = us2f((unsigned short)(w[threadIdx.x] & 0xFFFFu));
  float a = fabsf(v);
  if (a > 0.05f && a < 8.0f) atomicAdd(&cnt, 1);
  __syncthreads();
  if (threadIdx.x == 0) *flag = (cnt < 256) ? 1 : 0;   // 1 = f32 inputs, 0 = bf16
}

// ---------------- K0: convert / transpose weights to f32 in ws ----------------
__global__ void k_prep(const void* __restrict__ wqv,
                       const void* __restrict__ wk,
                       const void* __restrict__ fo,
                       const int* __restrict__ flag,
                       float* __restrict__ wT, float* __restrict__ qvb,
                       float* __restrict__ foT, float* __restrict__ fob,
                       float* __restrict__ wkf) {
  int isf = *flag;
  int stride = gridDim.x * blockDim.x;
  int idx = blockIdx.x * blockDim.x + threadIdx.x;
  for (int i = idx; i < OO * DD; i += stride) {        // wT[ii][o] = wqv[o][ii]
    int o = i & (OO - 1), ii = i >> 11;
    wT[i] = ldin(wqv, o * WCOLS + ii, isf);
  }
  for (int o = idx; o < OO; o += stride) qvb[o] = ldin(wqv, o * WCOLS + DD, isf);
  for (int i = idx; i < DD * DD; i += stride) {        // foT[ii][o] = fo[o][ii]
    int o = i & (DD - 1), ii = i >> 7;
    foT[i] = ldin(fo, o * WCOLS + ii, isf);
  }
  for (int o = idx; o < DD; o += stride) fob[o] = ldin(fo, o * WCOLS + DD, isf);
  for (int i = idx; i < HH * DD; i += stride) wkf[i] = ldin(wk, i, isf);
}

// ---------------- K1: QV projection GEMM -> q2u (quantized u16), v2 bf16 ----------------
__global__ __launch_bounds__(256) void k_qv(const void* __restrict__ x,
                                            const int* __restrict__ flag,
                                            const float* __restrict__ wT,
                                            const float* __restrict__ qvb,
                                            unsigned short* __restrict__ q2u,
                                            unsigned short* __restrict__ v2) {
  __shared__ __align__(16) float xs[16][132];   // pad 132: conflict-free row broadcast
  int isf = *flag;
  int m0 = blockIdx.x * 16;          // 256 row tiles
  int n0 = blockIdx.y * 128;         // 16 col tiles
  int tid = threadIdx.x;
#pragma unroll
  for (int p = 0; p < 8; ++p) {
    int e = tid + p * 256;
    int mr = e >> 7, i = e & 127;
    xs[mr][i] = ldin(x, (m0 + mr) * DD + i, isf);
  }
  __syncthreads();
  int ty = tid >> 5, tx = tid & 31;
  float acc[2][4] = {};
  const float* wp = wT + n0 + tx * 4;
  for (int i = 0; i < 128; ++i) {
    float4 w4 = *(const float4*)(wp + i * OO);
    float x0 = xs[ty * 2 + 0][i], x1 = xs[ty * 2 + 1][i];
    acc[0][0] += x0 * w4.x; acc[0][1] += x0 * w4.y; acc[0][2] += x0 * w4.z; acc[0][3] += x0 * w4.w;
    acc[1][0] += x1 * w4.x; acc[1][1] += x1 * w4.y; acc[1][2] += x1 * w4.z; acc[1][3] += x1 * w4.w;
  }
#pragma unroll
  for (int rr = 0; rr < 2; ++rr) {
    int r = m0 + ty * 2 + rr;
    int b = r >> 9, t = r & 511;
#pragma unroll
    for (int c = 0; c < 4; ++c) {
      int o = n0 + tx * 4 + c;
      float val = acc[rr][c] + qvb[o];
      int h = o >> 8, cc = o & 255;
      if (cc < DD) q2u[((b * HH + h) * TT + t) * DD + cc] = (unsigned short)quant1(val);
      else         v2[((b * HH + h) * TT + t) * DD + (cc - DD)] = f2us(val);
    }
  }
}

// ---------------- K1b: precompute quantized K: ku[b][h][s][d] u16 ----------------
__global__ void k_k(const void* __restrict__ x, const int* __restrict__ flag,
                    const float* __restrict__ wkf, unsigned short* __restrict__ ku) {
  int isf = *flag;
  int idx = blockIdx.x * 256 + threadIdx.x;     // 2^22 elements
  int d = idx & 127;
  int s = (idx >> 7) & 511;
  int h = (idx >> 16) & 7;
  int b = idx >> 19;
  float val = ldin(x, (b * TT + s) * DD + d, isf) * wkf[h * DD + d];
  ku[idx] = (unsigned short)quant1(val);
}

// ---------------- K1c: transpose V: v2[bh][t][d] -> vt[bh][d][t] ----------------
__global__ __launch_bounds__(256) void k_vt(const unsigned short* __restrict__ v2,
                                            unsigned short* __restrict__ vt) {
  __shared__ unsigned short tile[64][66];
  int t0 = blockIdx.x * 64;
  int d0 = blockIdx.y * 64;
  int bh = blockIdx.z;
  int tid = threadIdx.x;
  const unsigned short* src = v2 + ((size_t)bh * TT + t0) * DD + d0;
#pragma unroll
  for (int p = 0; p < 16; ++p) {
    int e = p * 256 + tid;
    int r = e >> 6, c = e & 63;
    tile[r][c] = src[r * DD + c];
  }
  __syncthreads();
  unsigned short* dst = vt + ((size_t)bh * DD + d0) * TT + t0;
#pragma unroll
  for (int p = 0; p < 16; ++p) {
    int e = p * 256 + tid;
    int r = e >> 6, c = e & 63;
    dst[r * TT + c] = tile[c][r];
  }
}

// ---------------- K2: fused L1-scores (v_sad_u16) + softmax*msk + MFMA apply ----------------
// grid (64, 32): blockIdx.x = bh (XCD pinning: id%8==h), blockIdx.y = i-tile.
// Whole K slice in LDS (rotated rows, ONE barrier). Score mapping: thread =
// (ig4 = tid>>6 -> i-rows 4*ig4..+3) x (ss = tid&63 -> s = c*64+ss). Per chunk:
// 8 independent b128 reads of ONE k-row feed 4 rows' SADs -> 2.7:1 VALU:LDS.
__global__ __launch_bounds__(256, 1) void k_flash(const void* __restrict__ msk,
                                                  const int* __restrict__ flag,
                                                  const unsigned short* __restrict__ q2u,
                                                  const unsigned short* __restrict__ ku,
                                                  const unsigned short* __restrict__ vt,
                                                  unsigned short* __restrict__ yo8) {
  extern __shared__ __align__(16) char smem[];
  unsigned int* kp = (unsigned int*)smem;                         // [512][66] rotated
  unsigned short* ps = (unsigned short*)(smem + KP_BYTES);        // [16][520]
  int isf = *flag;
  int bh = blockIdx.x;
  int h = bh & 7;
  int it0 = blockIdx.y * IT;
  int tid = threadIdx.x;

  // ---- stage ALL of k for this bh: 8192 uint4, coalesced, rotated rows ----
  // logical uint col u of row s stored at physical (u + 8*(s&7)) & 63
  const uint4* kc4 = (const uint4*)(ku + (size_t)bh * TT * DD);
#pragma unroll
  for (int p = 0; p < 32; ++p) {
    int e = tid + p * 256;
    int s = e >> 4, dq4 = e & 15;
    int pc = (dq4 * 4 + 8 * (s & 7)) & 63;
    *(uint4*)&kp[s * 66 + pc] = kc4[e];
  }
  __syncthreads();                    // the ONLY barrier before the score phase

  int ig4 = tid >> 6;                 // 0..3 -> rows 4*ig4 .. 4*ig4+3
  int ss = tid & 63;                  // s within chunk
  int rot = 8 * (ss & 7);             // rotation of this thread's k-rows

  int racc[4][8];
#pragma unroll
  for (int ii = 0; ii < 4; ++ii)
#pragma unroll
    for (int c = 0; c < 8; ++c) racc[ii][c] = 0;

  const uint4* qbase = (const uint4*)(q2u + ((size_t)bh * TT + it0 + 4 * ig4) * DD);
  // row ii is at qbase + ii*16 (128 u16 = 16 uint4 per row)

#pragma unroll 1
  for (int dh = 0; dh < 2; ++dh) {    // d-half outer: live q = 32 uint4
    uint4 qv[4][8];
#pragma unroll
    for (int ii = 0; ii < 4; ++ii)
#pragma unroll
      for (int j = 0; j < 8; ++j) qv[ii][j] = qbase[ii * 16 + dh * 8 + j];
#pragma unroll
    for (int c = 0; c < NC; ++c) {
      const unsigned int* kr = kp + (c * 64 + ss) * 66;
      uint4 kw[8];
#pragma unroll
      for (int j = 0; j < 8; ++j)     // 8 independent b128 reads, one k-row
        kw[j] = *(const uint4*)&kr[(dh * 32 + j * 4 + rot) & 63];
#pragma unroll
      for (int ii = 0; ii < 4; ++ii) {
        int a = racc[ii][c];
#pragma unroll
        for (int j = 0; j < 8; ++j) {
          a = SAD16(qv[ii][j].x, kw[j].x, a);
          a = SAD16(qv[ii][j].y, kw[j].y, a);
          a = SAD16(qv[ii][j].z, kw[j].z, a);
          a = SAD16(qv[ii][j].w, kw[j].w, a);
        }
        racc[ii][c] = a;
      }
    }
  }

  // scores -> float
  float rf[4][8];
#pragma unroll
  for (int ii = 0; ii < 4; ++ii)
#pragma unroll
    for (int c = 0; c < 8; ++c) rf[ii][c] = -(float)racc[ii][c] * SCALE_Q;

  // softmax per row over the full wave (width-64): row r's 512 scores live as
  // 8 chunk-values per lane across 64 lanes.
  float m[4], sum[4], inv[4];
#pragma unroll
  for (int ii = 0; ii < 4; ++ii) {
    float mm = rf[ii][0];
#pragma unroll
    for (int c = 1; c < 8; ++c) mm = fmaxf(mm, rf[ii][c]);
    m[ii] = mm;
  }
#pragma unroll
  for (int off = 32; off; off >>= 1)
#pragma unroll
    for (int ii = 0; ii < 4; ++ii) m[ii] = fmaxf(m[ii], __shfl_xor(m[ii], off, 64));
#pragma unroll
  for (int ii = 0; ii < 4; ++ii) {
    float s = 0.f;
#pragma unroll
    for (int c = 0; c < 8; ++c) { rf[ii][c] = __expf(rf[ii][c] - m[ii]); s += rf[ii][c]; }
    sum[ii] = s;
  }
#pragma unroll
  for (int off = 32; off; off >>= 1)
#pragma unroll
    for (int ii = 0; ii < 4; ++ii) sum[ii] += __shfl_xor(sum[ii], off, 64);
#pragma unroll
  for (int ii = 0; ii < 4; ++ii) inv[ii] = 1.0f / sum[ii];

  // write P = softmax * msk into ps (scalar u16; consecutive lanes -> consecutive cols)
#pragma unroll
  for (int ii = 0; ii < 4; ++ii) {
    int r = ig4 * 4 + ii;
    int mb = (h * TT + it0 + r) * TT;
#pragma unroll
    for (int c = 0; c < 8; ++c) {
      int s = c * 64 + ss;
      float p = rf[ii][c] * inv[ii] * ldin(msk, mb + s, isf);
      ps[r * (TT + 8) + s] = f2us(p);
    }
  }
  __syncthreads();

  // MFMA apply: bo(16x128) = P(16x512) . V(512x128), per-wave 32-col slice.
  {
    int lane = tid & 63;
    int w = tid >> 6;
    int mI = lane & 15;
    int quad = lane >> 4;
    int n0 = w * 32;
    floatx4 acc0 = {0.f, 0.f, 0.f, 0.f};
    floatx4 acc1 = {0.f, 0.f, 0.f, 0.f};
    const unsigned short* vb0 = vt + ((size_t)bh * DD + n0 + mI) * TT;
    const unsigned short* vb1 = vb0 + 16 * TT;
#pragma unroll
    for (int st = 0; st < 4; ++st) {
      short8 av[4], b0v[4], b1v[4];
#pragma unroll
      for (int j = 0; j < 4; ++j) {
        int krow = st * 128 + j * 32 + quad * 8;
        b0v[j] = *(const short8*)&vb0[krow];
        b1v[j] = *(const short8*)&vb1[krow];
        av[j]  = *(const short8*)&ps[mI * (TT + 8) + krow];
      }
#pragma unroll
      for (int j = 0; j < 4; ++j) {
        acc0 = __builtin_amdgcn_mfma_f32_16x16x32_bf16(av[j], b0v[j], acc0, 0, 0, 0);
        acc1 = __builtin_amdgcn_mfma_f32_16x16x32_bf16(av[j], b1v[j], acc1, 0, 0, 0);
      }
    }
    unsigned short* yb = yo8 + ((size_t)bh * TT + it0) * DD;
#pragma unroll
    for (int reg = 0; reg < 4; ++reg) {
      int row = quad * 4 + reg;
      yb[row * DD + n0 + mI]      = f2us(acc0[reg]);
      yb[row * DD + n0 + 16 + mI] = f2us(acc1[reg]);
    }
  }
}

// ---------------- K4: head-sum + gelu + fanout GEMM + residual -> out ----------------
__global__ __launch_bounds__(256) void k_fanout(const void* __restrict__ x,
                                                const int* __restrict__ flag,
                                                const unsigned short* __restrict__ yo8,
                                                const float* __restrict__ foT,
                                                const float* __restrict__ fob,
                                                void* __restrict__ outv) {
  __shared__ float ys[16][132];
  int isf = *flag;
  int m0 = blockIdx.x * 16;
  int tid = threadIdx.x;
#pragma unroll
  for (int p = 0; p < 8; ++p) {
    int e = tid + p * 256;
    int mr = e >> 7, ii = e & 127;
    int r = m0 + mr;
    int bb = r >> 9, t = r & 511;
    size_t base = ((size_t)bb * HH * TT + t) * DD + ii;   // + hh*TT*DD per head
    float sacc = 0.f;
#pragma unroll
    for (int hh = 0; hh < HH; ++hh) sacc += us2f(yo8[base + (size_t)hh * TT * DD]);
    float z = sacc + 4.5f;                                // + SUN/2
    ys[mr][ii] = z / (1.0f + __expf(-1.702f * z)) - 4.5f; // quick_gelu - SUN/2
  }
  __syncthreads();
  int ty = tid >> 5, tx = tid & 31;
  float acc[2][4] = {};
  for (int ii = 0; ii < 128; ++ii) {
    float4 w4 = *(const float4*)(foT + ii * DD + tx * 4);
    float y0 = ys[ty * 2 + 0][ii], y1 = ys[ty * 2 + 1][ii];
    acc[0][0] += y0 * w4.x; acc[0][1] += y0 * w4.y; acc[0][2] += y0 * w4.z; acc[0][3] += y0 * w4.w;
    acc[1][0] += y1 * w4.x; acc[1][1] += y1 * w4.y; acc[1][2] += y1 * w4.z; acc[1][3] += y1 * w4.w;
  }
#pragma unroll
  for (int rr = 0; rr < 2; ++rr) {
    int r = m0 + ty * 2 + rr;
#pragma unroll
    for (int c = 0; c < 4; ++c) {
      int o = tx * 4 + c;
      float val = acc[rr][c] + fob[o] + ldin(x, r * DD + o, isf);
      if (isf) ((float*)outv)[r * DD + o] = val;
      else     ((__hip_bfloat16*)outv)[r * DD + o] = __float2bfloat16(val);
    }
  }
}

extern "C" void kernel_launch(void* const* d_in, const int* in_sizes, int n_in,
                              void* d_out, int out_size, void* d_ws, size_t ws_size,
                              hipStream_t stream) {
  const void* x   = d_in[0];
  const void* msk = d_in[1];
  const void* wqv = d_in[2];
  const void* wk  = d_in[3];
  const void* fo  = d_in[4];

  // workspace carve-up: total ~33.2 MB
  float* wT  = (float*)d_ws;            // 262144 f32
  float* qvb = wT + 262144;             // 2048
  float* foT = qvb + 2048;              // 16384
  float* fob = foT + 16384;             // 128
  float* wkf = fob + 128;               // 1024
  int*   flg = (int*)(wkf + 1024);      // 16 (aligned pad)
  unsigned short* q2u = (unsigned short*)(flg + 16);  // 4194304 u16  [b][h][t][d] quantized q
  unsigned short* v2  = q2u + 4194304;                // 4194304 bf16 [b][h][t][d] (dead after k_vt)
  unsigned short* vt  = v2 + 4194304;                 // 4194304 bf16 [b][h][d][t]
  unsigned short* ku  = vt + 4194304;                 // 4194304 u16  [b][h][s][d] quantized k
  unsigned short* yo8 = v2;                           // reuse v2 as per-head bo [b][h][t][d]

  // allow >64 KB dynamic LDS for k_flash (idempotent, capture-safe)
  (void)hipFuncSetAttribute((const void*)k_flash,
                            hipFuncAttributeMaxDynamicSharedMemorySize, SH_BYTES);

  k_detect<<<1, 512, 0, stream>>>(x, flg);
  k_prep<<<256, 256, 0, stream>>>(wqv, wk, fo, flg, wT, qvb, foT, fob, wkf);
  k_qv<<<dim3(256, 16), 256, 0, stream>>>(x, flg, wT, qvb, q2u, v2);
  k_k<<<16384, 256, 0, stream>>>(x, flg, wkf, ku);
  k_vt<<<dim3(8, 2, 64), 256, 0, stream>>>(v2, vt);
  k_flash<<<dim3(64, 32), 256, SH_BYTES, stream>>>(msk, flg, q2u, ku, vt, yo8);
  k_fanout<<<256, 256, 0, stream>>>(x, flg, yo8, foT, fob, d_out);
}